// Round 1
// baseline (514.885 us; speedup 1.0000x reference)
//
#include <hip/hip_runtime.h>

// Conv1d as implicit GEMM on MFMA bf16.
// out[n,f,t] = sum_{c,k} x[n,c,t+k] * w[f,c,k] + b[f]
// N=32, C=64, W=4096, F=128, WW=64, out_W=4033. Output fp32.

#define N_BATCH 32
#define C_TOT   64
#define W_IN    4096
#define F_TOT   128
#define KW      64
#define OUT_W   4033
#define M_TILE  128   // t-values per block
#define WV_M    32    // t-rows per wave (2 x 16-row MFMA subtiles)

typedef __attribute__((ext_vector_type(8))) short  short8;
typedef __attribute__((ext_vector_type(4))) float  floatx4;

__device__ inline unsigned short f32_to_bf16(float f) {
  unsigned int u = __float_as_uint(f);
  u += 0x7FFF + ((u >> 16) & 1);   // round-to-nearest-even
  return (unsigned short)(u >> 16);
}

__global__ __launch_bounds__(256) void conv1d_mfma(
    const float* __restrict__ x, const float* __restrict__ w,
    const float* __restrict__ b, float* __restrict__ out) {
  // xs: sliding window of x for this (n, t-tile, c): t0 .. t0+190  (192 slots)
  __shared__ __align__(16) unsigned short xs[M_TILE + KW];      // 384 B
  __shared__ __align__(16) unsigned short wsh[F_TOT * KW];      // 16 KB, [f][k]

  const int tid  = threadIdx.x;
  const int lane = tid & 63;
  const int wv   = tid >> 6;      // 0..3
  const int q    = lane >> 4;     // 0..3
  const int col  = lane & 15;
  const int n    = blockIdx.y;
  const int t0   = blockIdx.x * M_TILE;

  floatx4 acc[2][8];
#pragma unroll
  for (int ms = 0; ms < 2; ++ms)
#pragma unroll
    for (int ft = 0; ft < 8; ++ft) acc[ms][ft] = (floatx4)0.0f;

  for (int c = 0; c < C_TOT; ++c) {
    __syncthreads();   // previous iteration's compute done before restage
    // stage x window (bounds-checked: tail tile reads past W; those feed only t>=out_W)
    if (tid < M_TILE + KW) {
      int gi = t0 + tid;
      float v = (gi < W_IN) ? x[((size_t)n * C_TOT + c) * W_IN + gi] : 0.0f;
      xs[tid] = f32_to_bf16(v);
    }
    // stage w[:, c, :] as [f][k] (== B^T layout); coalesced 64-float runs
#pragma unroll
    for (int i = tid; i < F_TOT * KW; i += 256) {
      int f = i >> 6, k = i & 63;
      wsh[i] = f32_to_bf16(w[((size_t)f * C_TOT + c) * KW + k]);
    }
    __syncthreads();

#pragma unroll
    for (int h = 0; h < 2; ++h) {         // two K=32 steps per channel
      // A fragments: A[m][kk] = xs[m + kk], m = wv*32 + ms*16 + col, kk = h*32 + q*8 + j
      int ab = col + wv * WV_M + h * 32 + q * 8;
      short8 a0, a1;
#pragma unroll
      for (int j = 0; j < 8; ++j) a0[j] = (short)xs[ab + j];
#pragma unroll
      for (int j = 0; j < 8; ++j) a1[j] = (short)xs[ab + 16 + j];
#pragma unroll
      for (int ft = 0; ft < 8; ++ft) {
        // B fragment: B[kk][f] = wsh[f*64 + kk], f = ft*16 + col — 16B aligned
        const short8 bf = *(const short8*)&wsh[(ft * 16 + col) * KW + h * 32 + q * 8];
        acc[0][ft] = __builtin_amdgcn_mfma_f32_16x16x32_bf16(a0, bf, acc[0][ft], 0, 0, 0);
        acc[1][ft] = __builtin_amdgcn_mfma_f32_16x16x32_bf16(a1, bf, acc[1][ft], 0, 0, 0);
      }
    }
  }

  // epilogue: D row = q*4 + r (t within 16-subtile), col = f within 16-subtile
#pragma unroll
  for (int ms = 0; ms < 2; ++ms) {
#pragma unroll
    for (int ft = 0; ft < 8; ++ft) {
      int f = ft * 16 + col;
      float bias = b[f];
      int tb = t0 + wv * WV_M + ms * 16 + q * 4;
      size_t obase = ((size_t)n * F_TOT + f) * OUT_W;
#pragma unroll
      for (int r = 0; r < 4; ++r) {
        int t = tb + r;
        if (t < OUT_W) out[obase + t] = acc[ms][ft][r] + bias;
      }
    }
  }
}

extern "C" void kernel_launch(void* const* d_in, const int* in_sizes, int n_in,
                              void* d_out, int out_size, void* d_ws, size_t ws_size,
                              hipStream_t stream) {
  const float* x = (const float*)d_in[0];
  const float* w = (const float*)d_in[1];
  const float* b = (const float*)d_in[2];
  float* out = (float*)d_out;
  dim3 grid((OUT_W + M_TILE - 1) / M_TILE, N_BATCH);  // 32 x 32
  conv1d_mfma<<<grid, 256, 0, stream>>>(x, w, b, out);
}

// Round 2
// 275.238 us; speedup vs baseline: 1.8707x; 1.8707x over previous
//
#include <hip/hip_runtime.h>

// Conv1d as implicit GEMM on MFMA bf16.
// out[n,f,t] = sum_{c,k} x[n,c,t+k] * w[f,c,k] + b[f]
// N=32, C=64, W=4096, F=128, WW=64, out_W=4033. Output fp32.
//
// R2: padded wsh stride (kills 16-way B-read bank conflict), 8 phase-shifted
// x-window replicas (A-fragments become aligned ds_read_b128), F split across
// 2 blocks (grid 2048 -> ~6 blocks/CU occupancy).

#define N_BATCH 32
#define C_TOT   64
#define W_IN    4096
#define F_TOT   128
#define KW      64
#define OUT_W   4033
#define M_TILE  128
#define F_TILE  64
#define WSTRIDE 72     // padded LDS row stride for w (shorts): 144 B = 36 dwords -> 2-way
#define XSTRIDE 200    // stride for x replicas (shorts): 400 B, 16B-aligned, 2-way

typedef __attribute__((ext_vector_type(8))) short  short8;
typedef __attribute__((ext_vector_type(4))) float  floatx4;

__device__ inline unsigned short f32_to_bf16(float f) {
  unsigned int u = __float_as_uint(f);
  u += 0x7FFF + ((u >> 16) & 1);   // round-to-nearest-even
  return (unsigned short)(u >> 16);
}

__global__ __launch_bounds__(256) void conv1d_mfma(
    const float* __restrict__ x, const float* __restrict__ w,
    const float* __restrict__ b, float* __restrict__ out) {
  __shared__ __align__(16) unsigned short wsh[F_TILE * WSTRIDE];   // 9216 B
  __shared__ __align__(16) unsigned short xrep[8 * XSTRIDE];       // 3200 B

  const int tid  = threadIdx.x;
  const int lane = tid & 63;
  const int wv   = tid >> 6;      // 0..3: wave -> 32-row t-slice
  const int q    = lane >> 4;     // 0..3
  const int col  = lane & 15;
  const int n    = blockIdx.y;
  const int t0   = blockIdx.x * M_TILE;
  const int fh   = blockIdx.z;    // 0/1: F half

  floatx4 acc[2][4];
#pragma unroll
  for (int ms = 0; ms < 2; ++ms)
#pragma unroll
    for (int ft = 0; ft < 4; ++ft) acc[ms][ft] = (floatx4)0.0f;

  // per-lane constant addresses
  const unsigned short* xb = &xrep[(col & 7) * XSTRIDE];  // base 400B-aligned (16B ok)
  const int cb = wv * 4 + q + (col >> 3);                 // A chunk base (8-short chunks)
  const int wl = tid >> 4;         // 0..15: f_loc base for w staging
  const int k4 = (tid & 15) * 4;   // 0..60: k base for w staging

  for (int c = 0; c < C_TOT; ++c) {
    __syncthreads();   // previous iteration's reads done before restage

    // --- stage x window as 8 phase-shifted bf16 replicas ---
    if (tid < M_TILE + KW) {
      int gi = t0 + tid;
      float v = (gi < W_IN) ? x[((size_t)n * C_TOT + c) * W_IN + gi] : 0.0f;
      unsigned short hv = f32_to_bf16(v);
#pragma unroll
      for (int r = 0; r < 8; ++r)
        if (tid >= r) xrep[r * XSTRIDE + tid - r] = hv;
    }

    // --- stage w[fh-half, c, :] as bf16 [f_loc][k], padded stride ---
#pragma unroll
    for (int s = 0; s < 4; ++s) {
      int f_loc = wl + 16 * s;
      const float4 v = *(const float4*)&w[((size_t)(fh * F_TILE + f_loc)) * (C_TOT * KW)
                                          + c * KW + k4];
      ushort4 o;
      o.x = f32_to_bf16(v.x); o.y = f32_to_bf16(v.y);
      o.z = f32_to_bf16(v.z); o.w = f32_to_bf16(v.w);
      *(ushort4*)&wsh[f_loc * WSTRIDE + k4] = o;
    }
    __syncthreads();

    // --- 2 K=32 steps, 16 MFMAs ---
#pragma unroll
    for (int h = 0; h < 2; ++h) {
      const short8 a0 = *(const short8*)&xb[(cb + h * 4 + 0) * 8];
      const short8 a1 = *(const short8*)&xb[(cb + h * 4 + 2) * 8];
#pragma unroll
      for (int ft = 0; ft < 4; ++ft) {
        const short8 bf = *(const short8*)&wsh[(ft * 16 + col) * WSTRIDE + h * 32 + q * 8];
        acc[0][ft] = __builtin_amdgcn_mfma_f32_16x16x32_bf16(a0, bf, acc[0][ft], 0, 0, 0);
        acc[1][ft] = __builtin_amdgcn_mfma_f32_16x16x32_bf16(a1, bf, acc[1][ft], 0, 0, 0);
      }
    }
  }

  // --- epilogue: D row = q*4 + r (t), col = f within 16-subtile ---
#pragma unroll
  for (int ms = 0; ms < 2; ++ms) {
#pragma unroll
    for (int ft = 0; ft < 4; ++ft) {
      int f = fh * F_TILE + ft * 16 + col;
      float bias = b[f];
      int tb = t0 + wv * 32 + ms * 16 + q * 4;
      size_t obase = ((size_t)n * F_TOT + f) * OUT_W;
#pragma unroll
      for (int r = 0; r < 4; ++r) {
        int t = tb + r;
        if (t < OUT_W) out[obase + t] = acc[ms][ft][r] + bias;
      }
    }
  }
}

extern "C" void kernel_launch(void* const* d_in, const int* in_sizes, int n_in,
                              void* d_out, int out_size, void* d_ws, size_t ws_size,
                              hipStream_t stream) {
  const float* x = (const float*)d_in[0];
  const float* w = (const float*)d_in[1];
  const float* b = (const float*)d_in[2];
  float* out = (float*)d_out;
  dim3 grid((OUT_W + M_TILE - 1) / M_TILE, N_BATCH, 2);  // 32 x 32 x 2 = 2048 blocks
  conv1d_mfma<<<grid, 256, 0, stream>>>(x, w, b, out);
}

// Round 3
// 248.765 us; speedup vs baseline: 2.0698x; 1.1064x over previous
//
#include <hip/hip_runtime.h>

// Conv1d as implicit GEMM on MFMA bf16 — R3.
// out[n,f,t] = sum_{c,k} x[n,c,t+k] * w[f,c,k] + b[f]
// N=32, C=64, W=4096, F=128, WW=64, out_W=4033. Output fp32.
//
// Two kernels:
//  prep: x -> bf16 (rows padded to 4352, zero-filled past 4095) in d_ws;
//        w -> bf16, swizzled layout [c][f][(k>>3)^(f&7)][k&7] in d_ws.
//  main: block = 256 t x 128 f, wave tile 64t x 128f (a=4 m-subtiles, b=8 f-subtiles
//        -> 0.375 b128/MFMA: MFMA-bound). CH=2 channels per iteration, K=128/iter,
//        single-barrier double-buffered global_load_lds staging.
//        Strided-t A mapping: t = t0 + 4*(col + 16*wv) + ms  -> all A LDS reads are
//        aligned ds_read_b64; ms-fragments built with compile-time funnel shifts.

#define C_TOT   64
#define F_TOT   128
#define KW      64
#define OUT_W   4033
#define W_IN    4096
#define N_BATCH 32
#define T_BLK   256
#define XROW    4352          // padded bf16 x row length (shorts)
#define CH      2             // channels per pipeline stage

typedef __attribute__((ext_vector_type(8))) short  short8;
typedef __attribute__((ext_vector_type(4))) float  floatx4;

union Frag { unsigned int u[4]; short8 v; };

__device__ inline unsigned short f32_to_bf16(float f) {
  unsigned int u = __float_as_uint(f);
  u += 0x7FFF + ((u >> 16) & 1);
  return (unsigned short)(u >> 16);
}

__device__ inline void async16(const unsigned short* g, unsigned short* l) {
  __builtin_amdgcn_global_load_lds(
      (const __attribute__((address_space(1))) unsigned int*)g,
      (__attribute__((address_space(3))) unsigned int*)l, 16, 0, 0);
}

// ---------------- prep: fp32 -> bf16 (+ w swizzle) ----------------
__global__ __launch_bounds__(256) void conv1d_prep(
    const float* __restrict__ x, const float* __restrict__ w,
    unsigned short* __restrict__ xb, unsigned short* __restrict__ wsw) {
  int bid = blockIdx.x;
  if (bid < N_BATCH * C_TOT) {              // x rows
    const float* src = x + (size_t)bid * W_IN;
    unsigned short* dst = xb + (size_t)bid * XROW;
    for (int i = threadIdx.x; i < XROW / 4; i += 256) {
      int t = i * 4;
      ushort4 o;
      if (t < W_IN) {
        float4 v = *(const float4*)(src + t);
        o.x = f32_to_bf16(v.x); o.y = f32_to_bf16(v.y);
        o.z = f32_to_bf16(v.z); o.w = f32_to_bf16(v.w);
      } else {
        o.x = o.y = o.z = o.w = 0;
      }
      *(ushort4*)(dst + t) = o;
    }
  } else {                                   // w: source layout [f][c][k]
    int wb = bid - N_BATCH * C_TOT;          // 0..63
    for (int i = wb * 256 + threadIdx.x; i < F_TOT * C_TOT * KW; i += 64 * 256) {
      int k = i & 63, c = (i >> 6) & 63, f = i >> 12;
      wsw[((size_t)(c * F_TOT + f) * 8 + ((k >> 3) ^ (f & 7))) * 8 + (k & 7)] =
          f32_to_bf16(w[i]);
    }
  }
}

// ---------------- main GEMM ----------------
__global__ __launch_bounds__(256, 2) void conv1d_mfma(
    const unsigned short* __restrict__ xb, const unsigned short* __restrict__ wsw,
    const float* __restrict__ b, float* __restrict__ out) {
  __shared__ __align__(16) unsigned short wls[2][CH * F_TOT * KW];  // 2 x 32 KB
  __shared__ __align__(16) unsigned short xls[2][CH * 512];         // 2 x 2 KB

  const int tid  = threadIdx.x;
  const int lane = tid & 63;
  const int wv   = tid >> 6;     // 0..3
  const int q    = lane >> 4;    // 0..3
  const int col  = lane & 15;
  const int n    = blockIdx.y;
  const int t0   = blockIdx.x * T_BLK;

  floatx4 acc[4][8];
#pragma unroll
  for (int ms = 0; ms < 4; ++ms)
#pragma unroll
    for (int ft = 0; ft < 8; ++ft) acc[ms][ft] = (floatx4)0.0f;

  // ---- staging (async global->LDS), issued per iteration, drained at barrier ----
  const unsigned short* xrow0 = xb + (size_t)(n * C_TOT) * XROW + t0;
#define STAGE(cg, p)                                                            \
  {                                                                             \
    const unsigned short* wbase = wsw + (size_t)(cg) * (CH * F_TOT * KW);       \
    _Pragma("unroll")                                                           \
    for (int s = 0; s < 8; ++s) {                                               \
      int off = (wv * 8 + s) * 512;                                             \
      async16(wbase + off + lane * 8, &wls[p][off]);                            \
    }                                                                           \
    if (wv < CH)                                                                \
      async16(xrow0 + (size_t)((cg) * CH + wv) * XROW + lane * 8,               \
              &xls[p][wv * 512]);                                               \
  }

  STAGE(0, 0)
  __syncthreads();

  for (int cg = 0; cg < C_TOT / CH; ++cg) {
    const int p = cg & 1;
    if (cg < C_TOT / CH - 1) STAGE(cg + 1, p ^ 1)

#pragma unroll
    for (int chl = 0; chl < CH; ++chl) {
      const unsigned short* xpb = &xls[p][chl * 512];
      const unsigned short* wpb = &wls[p][chl * F_TOT * KW];
#pragma unroll
      for (int h = 0; h < 2; ++h) {
        // A: 12-short span at byte offset 8*(col+16wv+2q+8h); 3 aligned b64 reads
        const int ab = (col + 16 * wv) * 8 + 16 * q + 64 * h;  // bytes
        unsigned int D[6];
#pragma unroll
        for (int s = 0; s < 3; ++s) {
          uint2 d2 = *(const uint2*)((const char*)xpb + ab + 8 * s);
          D[2 * s] = d2.x; D[2 * s + 1] = d2.y;
        }
        Frag A[4];
#pragma unroll
        for (int i = 0; i < 4; ++i) {
          A[0].u[i] = D[i];
          A[2].u[i] = D[i + 1];
          A[1].u[i] = (D[i] >> 16) | (D[i + 1] << 16);
          A[3].u[i] = (D[i + 1] >> 16) | (D[i + 2] << 16);
        }
        const int bs = ((h * 4 + q) ^ (col & 7)) * 8;  // swizzled k-chunk (shorts)
#pragma unroll
        for (int ft = 0; ft < 8; ++ft) {
          const short8 bf = *(const short8*)&wpb[(ft * 16 + col) * KW + bs];
          acc[0][ft] = __builtin_amdgcn_mfma_f32_16x16x32_bf16(A[0].v, bf, acc[0][ft], 0, 0, 0);
          acc[1][ft] = __builtin_amdgcn_mfma_f32_16x16x32_bf16(A[1].v, bf, acc[1][ft], 0, 0, 0);
          acc[2][ft] = __builtin_amdgcn_mfma_f32_16x16x32_bf16(A[2].v, bf, acc[2][ft], 0, 0, 0);
          acc[3][ft] = __builtin_amdgcn_mfma_f32_16x16x32_bf16(A[3].v, bf, acc[3][ft], 0, 0, 0);
        }
      }
    }
    __syncthreads();
  }

  // ---- epilogue: t = t0 + 4*(q*4+r + 16*wv) + ms ; f = ft*16+col ----
#pragma unroll
  for (int ft = 0; ft < 8; ++ft) {
    const int f = ft * 16 + col;
    const float bias = b[f];
    const size_t ob = ((size_t)n * F_TOT + f) * OUT_W;
#pragma unroll
    for (int ms = 0; ms < 4; ++ms) {
      const int tb = t0 + 4 * (q * 4 + 16 * wv) + ms;
#pragma unroll
      for (int r = 0; r < 4; ++r) {
        const int t = tb + 4 * r;
        if (t < OUT_W) out[ob + t] = acc[ms][ft][r] + bias;
      }
    }
  }
}

extern "C" void kernel_launch(void* const* d_in, const int* in_sizes, int n_in,
                              void* d_out, int out_size, void* d_ws, size_t ws_size,
                              hipStream_t stream) {
  const float* x = (const float*)d_in[0];
  const float* w = (const float*)d_in[1];
  const float* b = (const float*)d_in[2];
  float* out = (float*)d_out;

  unsigned short* wsw = (unsigned short*)d_ws;                     // 1 MB
  unsigned short* xb  = (unsigned short*)((char*)d_ws + (1 << 20)); // 17.8 MB

  conv1d_prep<<<N_BATCH * C_TOT + 64, 256, 0, stream>>>(x, w, xb, wsw);

  dim3 grid((OUT_W + T_BLK - 1) / T_BLK, N_BATCH);  // 16 x 32 = 512 blocks
  conv1d_mfma<<<grid, 256, 0, stream>>>(xb, wsw, b, out);
}